// Round 1
// baseline (703.680 us; speedup 1.0000x reference)
//
#include <hip/hip_runtime.h>
#include <stdint.h>
#include <stddef.h>

#define K_FULL 12544
#define M_ROWS 8192
#define NCLS 81
#define NREG 324
#define NTOT 405
#define NPAD 416
#define OUT0 663552      /* 8192*81 */
#define OUT_TOTAL 3317760 /* 8192*405 */

typedef __bf16 bf16x8 __attribute__((ext_vector_type(8)));
typedef float floatx4 __attribute__((ext_vector_type(4)));

__device__ __forceinline__ uint32_t pack2_bf16(float a, float b) {
  // round-to-nearest-even fp32 -> bf16, packed pair
  uint32_t ua = __float_as_uint(a);
  uint32_t ub = __float_as_uint(b);
  ua = (ua + 0x7FFFu + ((ua >> 16) & 1u)) >> 16;
  ub = (ub + 0x7FFFu + ((ub >> 16) & 1u)) >> 16;
  return ua | (ub << 16);
}

// ---------------------------------------------------------------------------
// Kernel 1: pack W_cls (81 x 12544) + W_reg (324 x 12544) fp32 -> bf16
// Wb[416][12544], rows 405..415 zero. Row-major, k contiguous.
// ---------------------------------------------------------------------------
__global__ void pack_w(const float* __restrict__ Wc, const float* __restrict__ Wr,
                       uint16_t* __restrict__ Wb) {
  const int u = blockIdx.x * blockDim.x + threadIdx.x; // 0..1791, valid < 1568
  if (u >= (K_FULL / 8)) return;
  const int row = blockIdx.y; // 0..415
  uint4 v = {0u, 0u, 0u, 0u};
  const float* src = nullptr;
  if (row < NCLS) src = Wc + (size_t)row * K_FULL;
  else if (row < NTOT) src = Wr + (size_t)(row - NCLS) * K_FULL;
  if (src) {
    const float4 f0 = *(const float4*)(src + u * 8);
    const float4 f1 = *(const float4*)(src + u * 8 + 4);
    v.x = pack2_bf16(f0.x, f0.y);
    v.y = pack2_bf16(f0.z, f0.w);
    v.z = pack2_bf16(f1.x, f1.y);
    v.w = pack2_bf16(f1.z, f1.w);
  }
  *(uint4*)(Wb + (size_t)row * K_FULL + u * 8) = v;
}

// ---------------------------------------------------------------------------
// Kernel 2: initialize d_out with the biases (K-split GEMM atomically adds).
// ---------------------------------------------------------------------------
__global__ void bias_init(const float* __restrict__ bc, const float* __restrict__ br,
                          float* __restrict__ out) {
  const int i = blockIdx.x * blockDim.x + threadIdx.x;
  if (i >= OUT_TOTAL) return;
  if (i < OUT0) {
    out[i] = bc[i % NCLS];
  } else {
    const int j = i - OUT0;
    out[i] = br[j % NREG];
  }
}

// ---------------------------------------------------------------------------
// Kernel 3: bf16 MFMA GEMM.
// Grid: 256 blocks = 64 M-tiles (128 rows) x 4 K-splits (3136 each).
// Block: 512 threads = 8 waves = 4 m-groups x 2 n-groups.
// Wave: 2 m-frags (16) x 13 n-frags (16) of mfma_f32_16x16x32_bf16.
// LDS: A tile 128x64 bf16 (reg-staged fp32->bf16), B tile 416x64 bf16
//      (global_load_lds width=16). 16B units XOR-swizzled by (row&7).
// ---------------------------------------------------------------------------
__global__ __launch_bounds__(512, 2) void gemm_kernel(
    const float* __restrict__ x, const uint16_t* __restrict__ Wb,
    float* __restrict__ out) {
  __shared__ uint4 sA4[1024]; // 16 KB
  __shared__ uint4 sB4[3328]; // 52 KB
  uint8_t* sA = (uint8_t*)sA4;
  uint8_t* sB = (uint8_t*)sB4;

  const int tid = threadIdx.x;
  const int lane = tid & 63;
  const int wave = tid >> 6; // 0..7
  const int mg = wave >> 1;  // 0..3
  const int ng = wave & 1;   // 0..1

  const int mt = blockIdx.x >> 2; // 0..63
  const int ks = blockIdx.x & 3;  // 0..3  (bid%8 keeps one K-quarter per XCD)
  const int rowBase = mt * 128;
  int k0 = ks * 3136;
  const int kEnd = k0 + 3136; // 49 chunks of 64

  floatx4 acc[2][13];
  const floatx4 zero = {0.0f, 0.0f, 0.0f, 0.0f};
#pragma unroll
  for (int i = 0; i < 2; ++i)
#pragma unroll
    for (int j = 0; j < 13; ++j) acc[i][j] = zero;

  const int rB = lane >> 3; // B-stage row within 8-row group
  const int pB = lane & 7;  // B-stage 16B unit position

  for (; k0 < kEnd; k0 += 64) {
    __syncthreads(); // LDS free from previous compute

    // ---- stage A: 128 rows x 64 k, fp32 -> bf16 (RNE), swizzled units ----
#pragma unroll
    for (int i = 0; i < 2; ++i) {
      const int U = tid + i * 512; // 0..1023 unit index
      const int m = U >> 3;        // 0..127
      const int p = U & 7;         // LDS unit position
      const int kb = p ^ (m & 7);  // global unit held at position p
      const float* g = x + (size_t)(rowBase + m) * K_FULL + (k0 + kb * 8);
      const float4 f0 = *(const float4*)g;
      const float4 f1 = *(const float4*)(g + 4);
      uint4 v;
      v.x = pack2_bf16(f0.x, f0.y);
      v.y = pack2_bf16(f0.z, f0.w);
      v.z = pack2_bf16(f1.x, f1.y);
      v.w = pack2_bf16(f1.z, f1.w);
      *(uint4*)(sA + m * 128 + p * 16) = v;
    }

    // ---- stage B: 416 rows x 64 k bf16 via global_load_lds (16B/lane) ----
    for (int i = wave; i < 52; i += 8) {
      const int n = i * 8 + rB;
      const int kb = pB ^ (n & 7);
      const uint16_t* g = Wb + (size_t)n * K_FULL + (k0 + kb * 8);
      __builtin_amdgcn_global_load_lds(
          (const __attribute__((address_space(1))) void*)g,
          (__attribute__((address_space(3))) void*)(sB + i * 1024), 16, 0, 0);
    }

    __syncthreads(); // drains vmcnt (global_load_lds) + lgkm (ds_write)

    // ---- compute: 2 K-steps of 32 ----
#pragma unroll
    for (int s = 0; s < 2; ++s) {
      const int q = lane >> 4;
      const int kb = s * 4 + q;
      const int m0 = mg * 32 + (lane & 15);
      const int m1 = m0 + 16;
      const bf16x8 a0 = *(const bf16x8*)(sA + m0 * 128 + ((kb ^ (m0 & 7)) * 16));
      const bf16x8 a1 = *(const bf16x8*)(sA + m1 * 128 + ((kb ^ (m1 & 7)) * 16));
#pragma unroll
      for (int nf = 0; nf < 13; ++nf) {
        const int n = ng * 208 + nf * 16 + (lane & 15);
        const bf16x8 b = *(const bf16x8*)(sB + n * 128 + ((kb ^ (n & 7)) * 16));
        acc[0][nf] = __builtin_amdgcn_mfma_f32_16x16x32_bf16(a0, b, acc[0][nf], 0, 0, 0);
        acc[1][nf] = __builtin_amdgcn_mfma_f32_16x16x32_bf16(a1, b, acc[1][nf], 0, 0, 0);
      }
    }
  }

  // ---- epilogue: scatter partials into split cls/reg outputs ----
  // C/D layout: col = lane&15, row = (lane>>4)*4 + reg  [m89/m91]
  const int q = lane >> 4;
  const int c0 = lane & 15;
#pragma unroll
  for (int fm = 0; fm < 2; ++fm) {
    const int r0 = rowBase + mg * 32 + fm * 16 + q * 4;
#pragma unroll
    for (int nf = 0; nf < 13; ++nf) {
      const int col = ng * 208 + nf * 16 + c0;
      if (col < NCLS) {
        float* dst = out + (size_t)r0 * NCLS + col;
#pragma unroll
        for (int r = 0; r < 4; ++r)
          unsafeAtomicAdd(dst + (size_t)r * NCLS, acc[fm][nf][r]);
      } else if (col < NTOT) {
        float* dst = out + OUT0 + (size_t)r0 * NREG + (col - NCLS);
#pragma unroll
        for (int r = 0; r < 4; ++r)
          unsafeAtomicAdd(dst + (size_t)r * NREG, acc[fm][nf][r]);
      }
    }
  }
}

extern "C" void kernel_launch(void* const* d_in, const int* in_sizes, int n_in,
                              void* d_out, int out_size, void* d_ws, size_t ws_size,
                              hipStream_t stream) {
  const float* x = (const float*)d_in[0];
  const float* Wc = (const float*)d_in[1];
  const float* bc = (const float*)d_in[2];
  const float* Wr = (const float*)d_in[3];
  const float* br = (const float*)d_in[4];
  float* out = (float*)d_out;
  uint16_t* Wb = (uint16_t*)d_ws; // 416*12544*2 = 10,436,608 B

  pack_w<<<dim3(7, 416), dim3(256), 0, stream>>>(Wc, Wr, Wb);
  bias_init<<<dim3((OUT_TOTAL + 255) / 256), dim3(256), 0, stream>>>(bc, br, out);
  gemm_kernel<<<dim3(256), dim3(512), 0, stream>>>(x, Wb, out);
}

// Round 2
// 657.762 us; speedup vs baseline: 1.0698x; 1.0698x over previous
//
#include <hip/hip_runtime.h>
#include <stdint.h>
#include <stddef.h>

#define K_FULL 12544
#define M_ROWS 8192
#define NCLS 81
#define NREG 324
#define NTOT 405
#define NPAD 416
#define OUT0 663552       /* 8192*81 */
#define OUT_TOTAL 3317760 /* 8192*405 */

typedef __bf16 bf16x8 __attribute__((ext_vector_type(8)));
typedef float floatx4 __attribute__((ext_vector_type(4)));

__device__ __forceinline__ uint32_t pack2_bf16(float a, float b) {
  // round-to-nearest-even fp32 -> bf16, packed pair
  uint32_t ua = __float_as_uint(a);
  uint32_t ub = __float_as_uint(b);
  ua = (ua + 0x7FFFu + ((ua >> 16) & 1u)) >> 16;
  ub = (ub + 0x7FFFu + ((ub >> 16) & 1u)) >> 16;
  return ua | (ub << 16);
}

// ---------------------------------------------------------------------------
// Kernel 1: pack W_cls (81 x 12544) + W_reg (324 x 12544) fp32 -> bf16
// Wb[416][12544], rows 405..415 zero. Row-major, k contiguous.
// ---------------------------------------------------------------------------
__global__ void pack_w(const float* __restrict__ Wc, const float* __restrict__ Wr,
                       uint16_t* __restrict__ Wb) {
  const int u = blockIdx.x * blockDim.x + threadIdx.x; // unit of 8 elems
  if (u >= (K_FULL / 8)) return;
  const int row = blockIdx.y; // 0..415
  uint4 v = {0u, 0u, 0u, 0u};
  const float* src = nullptr;
  if (row < NCLS) src = Wc + (size_t)row * K_FULL;
  else if (row < NTOT) src = Wr + (size_t)(row - NCLS) * K_FULL;
  if (src) {
    const float4 f0 = *(const float4*)(src + u * 8);
    const float4 f1 = *(const float4*)(src + u * 8 + 4);
    v.x = pack2_bf16(f0.x, f0.y);
    v.y = pack2_bf16(f0.z, f0.w);
    v.z = pack2_bf16(f1.x, f1.y);
    v.w = pack2_bf16(f1.z, f1.w);
  }
  *(uint4*)(Wb + (size_t)row * K_FULL + u * 8) = v;
}

// ---------------------------------------------------------------------------
// Kernel 2: initialize d_out with the biases (K-split GEMM atomically adds).
// ---------------------------------------------------------------------------
__global__ void bias_init(const float* __restrict__ bc, const float* __restrict__ br,
                          float* __restrict__ out) {
  const int i = blockIdx.x * blockDim.x + threadIdx.x;
  if (i >= OUT_TOTAL) return;
  if (i < OUT0) {
    out[i] = bc[i % NCLS];
  } else {
    const int j = i - OUT0;
    out[i] = br[j % NREG];
  }
}

// ---------------------------------------------------------------------------
// Kernel 3: bf16 MFMA GEMM.
// Grid: 512 blocks = 128 M-tiles (64 rows) x 4 K-splits (3136 each).
//   bid&3 = K-split -> each XCD (bid%8) sees one K-quarter of W; B-tile
//   (2.6 MB bf16) stays resident in that XCD's 4 MB L2.
// Block: 512 threads = 8 waves = 4 m-groups x 2 n-groups; wave = 1 m-frag
//   x 13 n-frags of mfma_f32_16x16x32_bf16 (acc = 52 fp32/lane).
// LDS: A 64x64 bf16 (8 KB, reg-staged fp32->bf16 with next-chunk register
//   prefetch), B 416x64 bf16 (52 KB via global_load_lds width=16).
//   Total 60 KB -> 2 blocks/CU; the second block's MFMA phase hides this
//   block's barrier drain (m114 co-scheduling).
// 16B LDS units XOR-swizzled by (row&7) -> conflict-free frag reads.
// ---------------------------------------------------------------------------
__global__ __launch_bounds__(512, 4) void gemm_kernel(
    const float* __restrict__ x, const uint16_t* __restrict__ Wb,
    float* __restrict__ out) {
  __shared__ uint4 sA4[512];  // 8 KB  : 64 rows x 8 units x 16 B
  __shared__ uint4 sB4[3328]; // 52 KB : 416 rows x 8 units x 16 B
  uint8_t* sA = (uint8_t*)sA4;
  uint8_t* sB = (uint8_t*)sB4;

  const int tid = threadIdx.x;
  const int lane = tid & 63;
  const int wave = tid >> 6; // 0..7
  const int mg = wave >> 1;  // 0..3 (16-row m-frag)
  const int ng = wave & 1;   // 0..1 (208-col n-half)

  const int mt = blockIdx.x >> 2; // 0..127
  const int ks = blockIdx.x & 3;  // 0..3
  const int rowBase = mt * 64;
  int k0 = ks * 3136;
  const int kEnd = k0 + 3136; // 49 chunks of 64

  floatx4 acc[13];
  const floatx4 zero = {0.0f, 0.0f, 0.0f, 0.0f};
#pragma unroll
  for (int j = 0; j < 13; ++j) acc[j] = zero;

  // A-staging geometry: thread -> one 16B LDS unit (8 bf16 = 8 fp32 source)
  const int mA = tid >> 3;          // 0..63 row
  const int pA = tid & 7;           // LDS unit position
  const int kbA = pA ^ (mA & 7);    // swizzled global unit
  const float* gA = x + (size_t)(rowBase + mA) * K_FULL + k0 + kbA * 8;

  // B-staging geometry (global_load_lds: wave-uniform LDS base + lane*16)
  const int rB = lane >> 3; // row within 8-row group
  const int pB = lane & 7;  // unit position
  const int kbB = pB ^ rB;  // swizzled global unit ((i*8+rB)&7 == rB)

  // prologue: prefetch first A chunk into registers
  float4 pf0 = *(const float4*)gA;
  float4 pf1 = *(const float4*)(gA + 4);
  gA += 64;

  for (; k0 < kEnd; k0 += 64) {
    __syncthreads(); // LDS free from previous compute

    // ---- commit prefetched A regs -> LDS (fp32 -> bf16 RNE) ----
    {
      uint4 v;
      v.x = pack2_bf16(pf0.x, pf0.y);
      v.y = pack2_bf16(pf0.z, pf0.w);
      v.z = pack2_bf16(pf1.x, pf1.y);
      v.w = pack2_bf16(pf1.z, pf1.w);
      *(uint4*)(sA + mA * 128 + pA * 16) = v;
    }

    // ---- stage B: 416 rows x 64 k bf16 via global_load_lds (16B/lane) ----
    for (int i = wave; i < 52; i += 8) {
      const int n = i * 8 + rB;
      const uint16_t* g = Wb + (size_t)n * K_FULL + (k0 + kbB * 8);
      __builtin_amdgcn_global_load_lds(
          (const __attribute__((address_space(1))) void*)g,
          (__attribute__((address_space(3))) void*)(sB + i * 1024), 16, 0, 0);
    }

    __syncthreads(); // drains vmcnt (global_load_lds) + lgkm (ds_write)

    // ---- prefetch next A chunk (overlaps with MFMA burst below) ----
    if (k0 + 64 < kEnd) {
      pf0 = *(const float4*)gA;
      pf1 = *(const float4*)(gA + 4);
      gA += 64;
    }

    // ---- compute: 2 K-steps of 32 ----
    const int q = lane >> 4;
    const int m0 = mg * 16 + (lane & 15);
#pragma unroll
    for (int s = 0; s < 2; ++s) {
      const int kb = s * 4 + q;
      const bf16x8 a0 = *(const bf16x8*)(sA + m0 * 128 + ((kb ^ (m0 & 7)) * 16));
#pragma unroll
      for (int nf = 0; nf < 13; ++nf) {
        const int n = ng * 208 + nf * 16 + (lane & 15);
        const bf16x8 b = *(const bf16x8*)(sB + n * 128 + ((kb ^ (n & 7)) * 16));
        acc[nf] = __builtin_amdgcn_mfma_f32_16x16x32_bf16(a0, b, acc[nf], 0, 0, 0);
      }
    }
  }

  // ---- epilogue: scatter partials into split cls/reg outputs ----
  // C/D layout: col = lane&15, row = (lane>>4)*4 + reg  [m89/m91]
  const int q = lane >> 4;
  const int c0 = lane & 15;
  const int r0 = rowBase + mg * 16 + q * 4;
#pragma unroll
  for (int nf = 0; nf < 13; ++nf) {
    const int col = ng * 208 + nf * 16 + c0;
    if (col < NCLS) {
      float* dst = out + (size_t)r0 * NCLS + col;
#pragma unroll
      for (int r = 0; r < 4; ++r)
        unsafeAtomicAdd(dst + (size_t)r * NCLS, acc[nf][r]);
    } else if (col < NTOT) {
      float* dst = out + OUT0 + (size_t)r0 * NREG + (col - NCLS);
#pragma unroll
      for (int r = 0; r < 4; ++r)
        unsafeAtomicAdd(dst + (size_t)r * NREG, acc[nf][r]);
    }
  }
}

extern "C" void kernel_launch(void* const* d_in, const int* in_sizes, int n_in,
                              void* d_out, int out_size, void* d_ws, size_t ws_size,
                              hipStream_t stream) {
  const float* x = (const float*)d_in[0];
  const float* Wc = (const float*)d_in[1];
  const float* bc = (const float*)d_in[2];
  const float* Wr = (const float*)d_in[3];
  const float* br = (const float*)d_in[4];
  float* out = (float*)d_out;
  uint16_t* Wb = (uint16_t*)d_ws; // 416*12544*2 = 10,436,608 B

  pack_w<<<dim3(7, 416), dim3(256), 0, stream>>>(Wc, Wr, Wb);
  bias_init<<<dim3((OUT_TOTAL + 255) / 256), dim3(256), 0, stream>>>(bc, br, out);
  gemm_kernel<<<dim3(512), dim3(512), 0, stream>>>(x, Wb, out);
}